// Round 9
// baseline (926.089 us; speedup 1.0000x reference)
//
#include <hip/hip_runtime.h>
#include <math.h>

// Problem constants (B=2, H=16, L=2048, D=128, fp32 in/out, int32 mask)
constexpr int Bc_ = 2;
constexpr int Hc_ = 16;
constexpr int Lc_ = 2048;
constexpr int Dc_ = 128;
constexpr int BR  = 128;  // Q rows per block (4 waves x 32 rows, 32x32 MFMA)
constexpr int BC  = 32;   // K rows per tile
// 1/sqrt(128) * log2(e): exp(x) == exp2(x*log2e); fold log2e into Q pre-scale.
constexpr float SCALE_LOG2E = 0.08838834764831845f * 1.4426950408889634f;

typedef __attribute__((ext_vector_type(8)))  short        bf16x8;
typedef __attribute__((ext_vector_type(4)))  float        f32x4;
typedef __attribute__((ext_vector_type(16))) float        f32x16;
typedef __attribute__((ext_vector_type(4)))  int          i32x4;
typedef __attribute__((ext_vector_type(4)))  unsigned int u32x4;

// fp32 -> bf16 RNE (scalar; only for the one-time Q fragment build)
__device__ __forceinline__ unsigned short f2bf(float f) {
  unsigned u = __builtin_bit_cast(unsigned, f);
  return (unsigned short)((u + 0x7fffu + ((u >> 16) & 1u)) >> 16);
}

// packed fp32x2 -> bf16x2 in ONE VALU op
__device__ __forceinline__ unsigned cvt_pk_bf16(float lo, float hi) {
  unsigned r;
  asm("v_cvt_pk_bf16_f32 %0, %1, %2" : "=v"(r) : "v"(lo), "v"(hi));
  return r;
}

// Workgroup barrier that does NOT drain vmcnt (unlike __syncthreads).
// LDS visibility needs lgkmcnt(0) only; register-prefetch global loads
// stay in flight across the barrier.
__device__ __forceinline__ void barrier_lgkm() {
  asm volatile("s_waitcnt lgkmcnt(0)\n\ts_barrier" ::: "memory");
}

constexpr int KS_STRIDE = 136;  // K tile rows (shorts)
constexpr int VT_STRIDE = 40;   // V^T rows (shorts, 32 k-cols + 8 pad)

// XOR swizzle (shorts): rows r, r+8, r+16, r+24 (same base bank-phase) get
// 4 distinct 16B slots. Applied identically on write and read (bijective,
// preserves 16B alignment). R7-verified; conflicts 2.4e7 -> 1.47e7.
__device__ __forceinline__ int swz(int row, int colShorts) {
  return colShorts ^ (((row >> 3) & 3) << 3);
}

// ===========================================================================
// R9 = R8 (best measured: total 855, attn ~290) + two HBM-delivery fixes:
// (a) PAIRED mask fetch: masks for two CONSECUTIVE tiles loaded back-to-back
//     -> 256 B (two adjacent L2 lines, same DRAM page) per mask row per
//     visit instead of 128 B ~5.4k cyc apart. Halves row-activates on the
//     dominant 537 MB mask stream. Mask regs 8 -> 16 i32x4 (+32 VGPR; cap
//     256 at (256,2), current use 120 -> safe, unlike R3's 170-cap spill).
// (b) XCD-aware block swizzle: default mapping gives xcd = qblk%8 -> every
//     XCD streams K/V of ALL 32 bh through its 4MB L2 (~100 MB over-fetch
//     seen in FETCH_SIZE). Bijective remap confines each XCD to 4 bh,
//     sequential in dispatch order -> 2MB/bh working set fits L2 (T1/m192).
// Math/layout identical to R8 (verified).
// ===========================================================================

// load masks for the tile pair starting at column KBN (this lane's q-row):
// cols KBN+hi*4+{0,8,16,24} and KBN+BC+hi*4+{0,8,16,24} (mbase_g folds hi*4)
#define LOADM8(MN, KBN)                                                       \
      MN##0 = __builtin_nontemporal_load((const i32x4*)(mbase_g + (KBN)));      \
      MN##1 = __builtin_nontemporal_load((const i32x4*)(mbase_g + (KBN) + 8));  \
      MN##2 = __builtin_nontemporal_load((const i32x4*)(mbase_g + (KBN) + 16)); \
      MN##3 = __builtin_nontemporal_load((const i32x4*)(mbase_g + (KBN) + 24)); \
      MN##4 = __builtin_nontemporal_load((const i32x4*)(mbase_g + (KBN) + BC));      \
      MN##5 = __builtin_nontemporal_load((const i32x4*)(mbase_g + (KBN) + BC + 8));  \
      MN##6 = __builtin_nontemporal_load((const i32x4*)(mbase_g + (KBN) + BC + 16)); \
      MN##7 = __builtin_nontemporal_load((const i32x4*)(mbase_g + (KBN) + BC + 24));

// one K-tile. M0..M3 = this tile's mask regs; MASKLOADS = LOADM8(...) on
// even tiles of a pair, `;` on odd tiles.
#define TILE_BODY(KB, M0, M1, M2, M3, MASKLOADS)                            \
  {                                                                         \
    /* 1. stage current K regs -> LDS (bf16, swizzled row-major) */         \
    {                                                                       \
      u32x4 a, b;                                                           \
      a[0] = cvt_pk_bf16(kr[0][0], kr[0][1]);                               \
      a[1] = cvt_pk_bf16(kr[0][2], kr[0][3]);                               \
      a[2] = cvt_pk_bf16(kr[1][0], kr[1][1]);                               \
      a[3] = cvt_pk_bf16(kr[1][2], kr[1][3]);                               \
      b[0] = cvt_pk_bf16(kr[2][0], kr[2][1]);                               \
      b[1] = cvt_pk_bf16(kr[2][2], kr[2][3]);                               \
      b[2] = cvt_pk_bf16(kr[3][0], kr[3][1]);                               \
      b[3] = cvt_pk_bf16(kr[3][2], kr[3][3]);                               \
      *(u32x4*)&Ks[krow * KS_STRIDE + swz(krow, kcg * 16)]     = a;         \
      *(u32x4*)&Ks[krow * KS_STRIDE + swz(krow, kcg * 16 + 8)] = b;         \
    }                                                                       \
    /* stage current V regs -> LDS transposed (scatter, swizzled) */        \
    _Pragma("unroll")                                                       \
    for (int c4 = 0; c4 < 4; ++c4) {                                        \
      const unsigned lov = cvt_pk_bf16(vr[c4][0], vr[c4][1]);               \
      const unsigned hiv = cvt_pk_bf16(vr[c4][2], vr[c4][3]);               \
      const int r0 = vcg * 16 + c4 * 4;                                     \
      Vt[(r0 + 0) * VT_STRIDE + swz(r0 + 0, vrow)] = (unsigned short)lov;   \
      Vt[(r0 + 1) * VT_STRIDE + swz(r0 + 1, vrow)] = (unsigned short)(lov >> 16); \
      Vt[(r0 + 2) * VT_STRIDE + swz(r0 + 2, vrow)] = (unsigned short)hiv;   \
      Vt[(r0 + 3) * VT_STRIDE + swz(r0 + 3, vrow)] = (unsigned short)(hiv >> 16); \
    }                                                                       \
    /* 2. issue next-tile K/V loads (1-deep) + paired mask loads (even      \
          tiles). All stay in flight across the lgkm-only barrier. */       \
    {                                                                       \
      const int kbn = ((KB) + BC) & (Lc_ - 1);                              \
      const float* kp = kbase_g + (size_t)kbn * Dc_;                        \
      const float* vp = vbase_g + (size_t)kbn * Dc_;                        \
      kr[0] = *(const f32x4*)(kp + 0);  kr[1] = *(const f32x4*)(kp + 4);    \
      kr[2] = *(const f32x4*)(kp + 8);  kr[3] = *(const f32x4*)(kp + 12);   \
      vr[0] = *(const f32x4*)(vp + 0);  vr[1] = *(const f32x4*)(vp + 4);    \
      vr[2] = *(const f32x4*)(vp + 8);  vr[3] = *(const f32x4*)(vp + 12);   \
      MASKLOADS                                                             \
    }                                                                       \
    /* 3. barrier (lgkm only) — publishes Ks/Vt */                          \
    barrier_lgkm();                                                         \
    /* 4. S^T = K (Q*scale)^T : one 32x32 tile, 8 chained MFMAs over d */   \
    f32x16 s = (f32x16)0.0f;                                                \
    __builtin_amdgcn_s_setprio(1);                                          \
    _Pragma("unroll")                                                       \
    for (int st = 0; st < 8; ++st) {                                        \
      const bf16x8 kf = *(const bf16x8*)&Ks[l31 * KS_STRIDE + swz(l31, st * 16 + hi8)]; \
      s = __builtin_amdgcn_mfma_f32_32x32x16_bf16(kf, qf[st], s, 0, 0, 0);  \
    }                                                                       \
    __builtin_amdgcn_s_setprio(0);                                          \
    /* 5. p = mask ? exp2(s) : 0 ; per-lane scalar row-sum; PV A-frags in   \
          register via cvt_pk + cross-half exchange (no LDS). */            \
    bf16x8 pa0, pa1;                                                        \
    {                                                                       \
      const float p0  = ((M0)[0] != 0) ? exp2f(s[0])  : 0.0f;               \
      const float p1  = ((M0)[1] != 0) ? exp2f(s[1])  : 0.0f;               \
      const float p2  = ((M0)[2] != 0) ? exp2f(s[2])  : 0.0f;               \
      const float p3  = ((M0)[3] != 0) ? exp2f(s[3])  : 0.0f;               \
      const float p4  = ((M1)[0] != 0) ? exp2f(s[4])  : 0.0f;               \
      const float p5  = ((M1)[1] != 0) ? exp2f(s[5])  : 0.0f;               \
      const float p6  = ((M1)[2] != 0) ? exp2f(s[6])  : 0.0f;               \
      const float p7  = ((M1)[3] != 0) ? exp2f(s[7])  : 0.0f;               \
      const float p8  = ((M2)[0] != 0) ? exp2f(s[8])  : 0.0f;               \
      const float p9  = ((M2)[1] != 0) ? exp2f(s[9])  : 0.0f;               \
      const float p10 = ((M2)[2] != 0) ? exp2f(s[10]) : 0.0f;               \
      const float p11 = ((M2)[3] != 0) ? exp2f(s[11]) : 0.0f;               \
      const float p12 = ((M3)[0] != 0) ? exp2f(s[12]) : 0.0f;               \
      const float p13 = ((M3)[1] != 0) ? exp2f(s[13]) : 0.0f;               \
      const float p14 = ((M3)[2] != 0) ? exp2f(s[14]) : 0.0f;               \
      const float p15 = ((M3)[3] != 0) ? exp2f(s[15]) : 0.0f;               \
      lsum += (((p0 + p1) + (p2 + p3)) + ((p4 + p5) + (p6 + p7)))           \
            + (((p8 + p9) + (p10 + p11)) + ((p12 + p13) + (p14 + p15)));    \
      const unsigned c0 = cvt_pk_bf16(p0,  p1),  c1 = cvt_pk_bf16(p2,  p3); \
      const unsigned c2 = cvt_pk_bf16(p4,  p5),  c3 = cvt_pk_bf16(p6,  p7); \
      const unsigned c4 = cvt_pk_bf16(p8,  p9),  c5 = cvt_pk_bf16(p10, p11);\
      const unsigned c6 = cvt_pk_bf16(p12, p13), c7 = cvt_pk_bf16(p14, p15);\
      const unsigned x0 = (unsigned)__shfl_xor((int)c0, 32);                \
      const unsigned x1 = (unsigned)__shfl_xor((int)c1, 32);                \
      const unsigned x2 = (unsigned)__shfl_xor((int)c2, 32);                \
      const unsigned x3 = (unsigned)__shfl_xor((int)c3, 32);                \
      const unsigned x4 = (unsigned)__shfl_xor((int)c4, 32);                \
      const unsigned x5 = (unsigned)__shfl_xor((int)c5, 32);                \
      const unsigned x6 = (unsigned)__shfl_xor((int)c6, 32);                \
      const unsigned x7 = (unsigned)__shfl_xor((int)c7, 32);                \
      u32x4 a0, a1;                                                         \
      a0[0] = lo ? c0 : x2;  a0[1] = lo ? c1 : x3;                          \
      a0[2] = lo ? x0 : c2;  a0[3] = lo ? x1 : c3;                          \
      a1[0] = lo ? c4 : x6;  a1[1] = lo ? c5 : x7;                          \
      a1[2] = lo ? x4 : c6;  a1[3] = lo ? x5 : c7;                          \
      pa0 = __builtin_bit_cast(bf16x8, a0);                                 \
      pa1 = __builtin_bit_cast(bf16x8, a1);                                 \
    }                                                                       \
    /* 6. O += P V : 4 d-blocks x 2 k-halves, B = V^T rows from LDS */      \
    __builtin_amdgcn_s_setprio(1);                                          \
    _Pragma("unroll")                                                       \
    for (int nb = 0; nb < 4; ++nb) {                                        \
      const int vrw0 = nb * 32 + l31;                                       \
      const bf16x8 vf0 = *(const bf16x8*)&Vt[vrw0 * VT_STRIDE + swz(vrw0, hi8)]; \
      acc[nb] = __builtin_amdgcn_mfma_f32_32x32x16_bf16(pa0, vf0, acc[nb], 0, 0, 0); \
      const bf16x8 vf1 = *(const bf16x8*)&Vt[vrw0 * VT_STRIDE + swz(vrw0, 16 + hi8)]; \
      acc[nb] = __builtin_amdgcn_mfma_f32_32x32x16_bf16(pa1, vf1, acc[nb], 0, 0, 0); \
    }                                                                       \
    __builtin_amdgcn_s_setprio(0);                                          \
    /* 7. protect LDS before next overwrite */                              \
    barrier_lgkm();                                                         \
  }

// launch_bounds(256, 2): ~152 est. live regs (was 120 + 32 paired-mask).
// DO NOT raise waves/EU: (256,4) spilled 2.5 GB/dispatch (measured twice);
// (256,3) spilled 3-deep prefetch (R3). Grid 512 = exactly 2 blocks/CU.
// LDS: Ks 8704 + Vt 10240 = 18944 B.
__global__ __launch_bounds__(256, 2) void attn_fwd(
    const float* __restrict__ Q, const float* __restrict__ K,
    const float* __restrict__ V, const int* __restrict__ Mask,
    float* __restrict__ Out) {
  // XCD-aware bijective decode: xcd = id%8 (HW round-robin). Each XCD gets
  // bh in [4*xcd, 4*xcd+4), qblk sequential -> K/V (2MB/bh) L2-resident.
  const int id   = blockIdx.x;
  const int xcd  = id & 7;
  const int sub  = id >> 3;          // 0..63
  const int bh   = xcd * 4 + (sub >> 4);
  const int qblk = sub & 15;

  const int tid  = threadIdx.x;
  const int w    = tid >> 6;
  const int lane = tid & 63;
  const int l31  = lane & 31;
  const int hi   = lane >> 5;
  const int hi8  = hi * 8;
  const bool lo  = (hi == 0);

  const float* Qg = Q + (size_t)bh * Lc_ * Dc_;
  const float* Kg = K + (size_t)bh * Lc_ * Dc_;
  const float* Vg = V + (size_t)bh * Lc_ * Dc_;
  const int*   Mg = Mask + (size_t)bh * Lc_ * Lc_;
  float*       Og = Out + (size_t)bh * Lc_ * Dc_;

  const int qr0 = qblk * BR + w * 32;

  __shared__ alignas(16) unsigned short Ks[BC * KS_STRIDE];
  __shared__ alignas(16) unsigned short Vt[Dc_ * VT_STRIDE];

  // ---- Q fragments (B-operand of 32x32x16), loaded once, pre-scaled ----
  bf16x8 qf[8];
  {
    const float* qrow = Qg + (size_t)(qr0 + l31) * Dc_ + hi8;
#pragma unroll
    for (int st = 0; st < 8; ++st) {
      const f32x4 a = *(const f32x4*)(qrow + st * 16);
      const f32x4 b = *(const f32x4*)(qrow + st * 16 + 4);
      bf16x8 f;
      f[0] = (short)f2bf(a[0] * SCALE_LOG2E); f[1] = (short)f2bf(a[1] * SCALE_LOG2E);
      f[2] = (short)f2bf(a[2] * SCALE_LOG2E); f[3] = (short)f2bf(a[3] * SCALE_LOG2E);
      f[4] = (short)f2bf(b[0] * SCALE_LOG2E); f[5] = (short)f2bf(b[1] * SCALE_LOG2E);
      f[6] = (short)f2bf(b[2] * SCALE_LOG2E); f[7] = (short)f2bf(b[3] * SCALE_LOG2E);
      qf[st] = f;
    }
  }

  f32x16 acc[4];
#pragma unroll
  for (int i = 0; i < 4; ++i) acc[i] = (f32x16)0.0f;
  float lsum = 0.0f;

  const int krow = tid >> 3;   // 0..31, 8 threads/row (coalesced 64B)
  const int kcg  = tid & 7;
  const int vrow = tid & 31;
  const int vcg  = tid >> 5;

  const float* kbase_g = Kg + (size_t)krow * Dc_ + kcg * 16;
  const float* vbase_g = Vg + (size_t)vrow * Dc_ + vcg * 16;
  const int*   mbase_g = Mg + (size_t)(qr0 + l31) * Lc_ + hi * 4;

  f32x4 kr[4], vr[4];
  // paired mask sets: mP holds tiles {2t, 2t+1}, mN the next pair.
  i32x4 mP0, mP1, mP2, mP3, mP4, mP5, mP6, mP7;
  i32x4 mN0, mN1, mN2, mN3, mN4, mN5, mN6, mN7;

  kr[0] = *(const f32x4*)(kbase_g + 0);  kr[1] = *(const f32x4*)(kbase_g + 4);
  kr[2] = *(const f32x4*)(kbase_g + 8);  kr[3] = *(const f32x4*)(kbase_g + 12);
  vr[0] = *(const f32x4*)(vbase_g + 0);  vr[1] = *(const f32x4*)(vbase_g + 4);
  vr[2] = *(const f32x4*)(vbase_g + 8);  vr[3] = *(const f32x4*)(vbase_g + 12);
  LOADM8(mP, 0)

#pragma unroll 1
  for (int kb = 0; kb < Lc_; kb += 4 * BC) {
    TILE_BODY(kb,          mP0, mP1, mP2, mP3, LOADM8(mN, ((kb + 2 * BC) & (Lc_ - 1))))
    TILE_BODY(kb + BC,     mP4, mP5, mP6, mP7, ;)
    TILE_BODY(kb + 2 * BC, mN0, mN1, mN2, mN3, LOADM8(mP, ((kb + 4 * BC) & (Lc_ - 1))))
    TILE_BODY(kb + 3 * BC, mN4, mN5, mN6, mN7, ;)
  }

  // ---- epilogue: combine k-halves' sums, normalize, store ----
  lsum += __shfl_xor(lsum, 32);
  const float inv = 1.0f / lsum;
#pragma unroll
  for (int r = 0; r < 16; ++r) {
    const int qrow_r = (r & 3) + 8 * (r >> 2) + 4 * hi;
    const float rinv = __shfl(inv, qrow_r);
    float* orow = Og + (size_t)(qr0 + qrow_r) * Dc_ + l31;
#pragma unroll
    for (int nb = 0; nb < 4; ++nb)
      __builtin_nontemporal_store(acc[nb][r] * rinv, orow + nb * 32);
  }
}

extern "C" void kernel_launch(void* const* d_in, const int* in_sizes, int n_in,
                              void* d_out, int out_size, void* d_ws, size_t ws_size,
                              hipStream_t stream) {
  const float* Q    = (const float*)d_in[0];
  const float* K    = (const float*)d_in[1];
  const float* V    = (const float*)d_in[2];
  const int*   Mask = (const int*)d_in[3];
  float*       Out  = (float*)d_out;
  (void)d_ws; (void)ws_size;
  attn_fwd<<<dim3(512), dim3(256), 0, stream>>>(Q, K, V, Mask, Out);
}

// Round 10
// 844.054 us; speedup vs baseline: 1.0972x; 1.0972x over previous
//
#include <hip/hip_runtime.h>
#include <math.h>

// Problem constants (B=2, H=16, L=2048, D=128, fp32 in/out, int32 mask)
constexpr int Bc_ = 2;
constexpr int Hc_ = 16;
constexpr int Lc_ = 2048;
constexpr int Dc_ = 128;
constexpr int BR  = 128;  // Q rows per block (4 waves x 32 rows, 32x32 MFMA)
constexpr int BC  = 32;   // K rows per tile
// 1/sqrt(128) * log2(e): exp(x) == exp2(x*log2e); fold log2e into Q pre-scale.
constexpr float SCALE_LOG2E = 0.08838834764831845f * 1.4426950408889634f;

typedef __attribute__((ext_vector_type(8)))  short        bf16x8;
typedef __attribute__((ext_vector_type(4)))  float        f32x4;
typedef __attribute__((ext_vector_type(16))) float        f32x16;
typedef __attribute__((ext_vector_type(4)))  int          i32x4;
typedef __attribute__((ext_vector_type(4)))  unsigned int u32x4;

// fp32 -> bf16 RNE (scalar; only for the one-time Q fragment build)
__device__ __forceinline__ unsigned short f2bf(float f) {
  unsigned u = __builtin_bit_cast(unsigned, f);
  return (unsigned short)((u + 0x7fffu + ((u >> 16) & 1u)) >> 16);
}

// packed fp32x2 -> bf16x2 in ONE VALU op
__device__ __forceinline__ unsigned cvt_pk_bf16(float lo, float hi) {
  unsigned r;
  asm("v_cvt_pk_bf16_f32 %0, %1, %2" : "=v"(r) : "v"(lo), "v"(hi));
  return r;
}

// Workgroup barrier that does NOT drain vmcnt (unlike __syncthreads).
// LDS visibility needs lgkmcnt(0) only; register-prefetch global loads
// stay in flight across the barrier.
__device__ __forceinline__ void barrier_lgkm() {
  asm volatile("s_waitcnt lgkmcnt(0)\n\ts_barrier" ::: "memory");
}

constexpr int KS_STRIDE = 136;  // K tile rows (shorts)
constexpr int VT_STRIDE = 40;   // V^T rows (shorts, 32 k-cols + 8 pad)

// XOR swizzle (shorts): rows r, r+8, r+16, r+24 (same base bank-phase) get
// 4 distinct 16B slots. Applied identically on write and read (bijective,
// preserves 16B alignment). R7-verified; conflicts 2.4e7 -> 1.47e7.
__device__ __forceinline__ int swz(int row, int colShorts) {
  return colShorts ^ (((row >> 3) & 3) << 3);
}

// ===========================================================================
// R10 = R8 (best measured: total 855, attn ~290) + XCD-aware block swizzle
// ONLY. R9 isolated the two R9 changes:
//   - paired-mask prefetch (16 i32x4): SPILLED (VGPR 128 + WRITE 134 MB,
//     +60us) -> REVERTED. Register budget for prefetch state is ~128 arch
//     VGPRs total; 8 x i32x4 mask regs is the max (3rd spill occurrence).
//   - XCD swizzle: FETCH 651 -> 391 MB even with spill traffic inside it
//     (breaks cyclic-LRU thrash of the 537MB mask stream through the 256MB
//     L3 across dispatches + confines K/V per XCD) -> KEPT.
// Math/layout identical to R8 (verified).
// ===========================================================================
#define TILE_BODY(KB, MC, MN)                                               \
  {                                                                         \
    /* 1. stage current K regs -> LDS (bf16, swizzled row-major) */         \
    {                                                                       \
      u32x4 a, b;                                                           \
      a[0] = cvt_pk_bf16(kr[0][0], kr[0][1]);                               \
      a[1] = cvt_pk_bf16(kr[0][2], kr[0][3]);                               \
      a[2] = cvt_pk_bf16(kr[1][0], kr[1][1]);                               \
      a[3] = cvt_pk_bf16(kr[1][2], kr[1][3]);                               \
      b[0] = cvt_pk_bf16(kr[2][0], kr[2][1]);                               \
      b[1] = cvt_pk_bf16(kr[2][2], kr[2][3]);                               \
      b[2] = cvt_pk_bf16(kr[3][0], kr[3][1]);                               \
      b[3] = cvt_pk_bf16(kr[3][2], kr[3][3]);                               \
      *(u32x4*)&Ks[krow * KS_STRIDE + swz(krow, kcg * 16)]     = a;         \
      *(u32x4*)&Ks[krow * KS_STRIDE + swz(krow, kcg * 16 + 8)] = b;         \
    }                                                                       \
    /* stage current V regs -> LDS transposed (scatter, swizzled) */        \
    _Pragma("unroll")                                                       \
    for (int c4 = 0; c4 < 4; ++c4) {                                        \
      const unsigned lov = cvt_pk_bf16(vr[c4][0], vr[c4][1]);               \
      const unsigned hiv = cvt_pk_bf16(vr[c4][2], vr[c4][3]);               \
      const int r0 = vcg * 16 + c4 * 4;                                     \
      Vt[(r0 + 0) * VT_STRIDE + swz(r0 + 0, vrow)] = (unsigned short)lov;   \
      Vt[(r0 + 1) * VT_STRIDE + swz(r0 + 1, vrow)] = (unsigned short)(lov >> 16); \
      Vt[(r0 + 2) * VT_STRIDE + swz(r0 + 2, vrow)] = (unsigned short)hiv;   \
      Vt[(r0 + 3) * VT_STRIDE + swz(r0 + 3, vrow)] = (unsigned short)(hiv >> 16); \
    }                                                                       \
    /* 2. issue next-tile K/V + mask loads (1-deep). All stay in flight     \
          across the lgkm-only barrier; tile body (~5k cyc) covers latency. */ \
    {                                                                       \
      const int kbn = ((KB) + BC) & (Lc_ - 1);                              \
      const float* kp = kbase_g + (size_t)kbn * Dc_;                        \
      const float* vp = vbase_g + (size_t)kbn * Dc_;                        \
      kr[0] = *(const f32x4*)(kp + 0);  kr[1] = *(const f32x4*)(kp + 4);    \
      kr[2] = *(const f32x4*)(kp + 8);  kr[3] = *(const f32x4*)(kp + 12);   \
      vr[0] = *(const f32x4*)(vp + 0);  vr[1] = *(const f32x4*)(vp + 4);    \
      vr[2] = *(const f32x4*)(vp + 8);  vr[3] = *(const f32x4*)(vp + 12);   \
      MN##0 = __builtin_nontemporal_load((const i32x4*)(mbase_g + kbn));      \
      MN##1 = __builtin_nontemporal_load((const i32x4*)(mbase_g + kbn + 8));  \
      MN##2 = __builtin_nontemporal_load((const i32x4*)(mbase_g + kbn + 16)); \
      MN##3 = __builtin_nontemporal_load((const i32x4*)(mbase_g + kbn + 24)); \
    }                                                                       \
    /* 3. barrier (lgkm only) — publishes Ks/Vt */                          \
    barrier_lgkm();                                                         \
    /* 4. S^T = K (Q*scale)^T : one 32x32 tile, 8 chained MFMAs over d */   \
    f32x16 s = (f32x16)0.0f;                                                \
    __builtin_amdgcn_s_setprio(1);                                          \
    _Pragma("unroll")                                                       \
    for (int st = 0; st < 8; ++st) {                                        \
      const bf16x8 kf = *(const bf16x8*)&Ks[l31 * KS_STRIDE + swz(l31, st * 16 + hi8)]; \
      s = __builtin_amdgcn_mfma_f32_32x32x16_bf16(kf, qf[st], s, 0, 0, 0);  \
    }                                                                       \
    __builtin_amdgcn_s_setprio(0);                                          \
    /* 5. p = mask ? exp2(s) : 0 ; per-lane scalar row-sum; PV A-frags in   \
          register via cvt_pk + cross-half exchange (no LDS). */            \
    bf16x8 pa0, pa1;                                                        \
    {                                                                       \
      const float p0  = ((MC##0)[0] != 0) ? exp2f(s[0])  : 0.0f;            \
      const float p1  = ((MC##0)[1] != 0) ? exp2f(s[1])  : 0.0f;            \
      const float p2  = ((MC##0)[2] != 0) ? exp2f(s[2])  : 0.0f;            \
      const float p3  = ((MC##0)[3] != 0) ? exp2f(s[3])  : 0.0f;            \
      const float p4  = ((MC##1)[0] != 0) ? exp2f(s[4])  : 0.0f;            \
      const float p5  = ((MC##1)[1] != 0) ? exp2f(s[5])  : 0.0f;            \
      const float p6  = ((MC##1)[2] != 0) ? exp2f(s[6])  : 0.0f;            \
      const float p7  = ((MC##1)[3] != 0) ? exp2f(s[7])  : 0.0f;            \
      const float p8  = ((MC##2)[0] != 0) ? exp2f(s[8])  : 0.0f;            \
      const float p9  = ((MC##2)[1] != 0) ? exp2f(s[9])  : 0.0f;            \
      const float p10 = ((MC##2)[2] != 0) ? exp2f(s[10]) : 0.0f;            \
      const float p11 = ((MC##2)[3] != 0) ? exp2f(s[11]) : 0.0f;            \
      const float p12 = ((MC##3)[0] != 0) ? exp2f(s[12]) : 0.0f;            \
      const float p13 = ((MC##3)[1] != 0) ? exp2f(s[13]) : 0.0f;            \
      const float p14 = ((MC##3)[2] != 0) ? exp2f(s[14]) : 0.0f;            \
      const float p15 = ((MC##3)[3] != 0) ? exp2f(s[15]) : 0.0f;            \
      lsum += (((p0 + p1) + (p2 + p3)) + ((p4 + p5) + (p6 + p7)))           \
            + (((p8 + p9) + (p10 + p11)) + ((p12 + p13) + (p14 + p15)));    \
      const unsigned c0 = cvt_pk_bf16(p0,  p1),  c1 = cvt_pk_bf16(p2,  p3); \
      const unsigned c2 = cvt_pk_bf16(p4,  p5),  c3 = cvt_pk_bf16(p6,  p7); \
      const unsigned c4 = cvt_pk_bf16(p8,  p9),  c5 = cvt_pk_bf16(p10, p11);\
      const unsigned c6 = cvt_pk_bf16(p12, p13), c7 = cvt_pk_bf16(p14, p15);\
      const unsigned x0 = (unsigned)__shfl_xor((int)c0, 32);                \
      const unsigned x1 = (unsigned)__shfl_xor((int)c1, 32);                \
      const unsigned x2 = (unsigned)__shfl_xor((int)c2, 32);                \
      const unsigned x3 = (unsigned)__shfl_xor((int)c3, 32);                \
      const unsigned x4 = (unsigned)__shfl_xor((int)c4, 32);                \
      const unsigned x5 = (unsigned)__shfl_xor((int)c5, 32);                \
      const unsigned x6 = (unsigned)__shfl_xor((int)c6, 32);                \
      const unsigned x7 = (unsigned)__shfl_xor((int)c7, 32);                \
      u32x4 a0, a1;                                                         \
      a0[0] = lo ? c0 : x2;  a0[1] = lo ? c1 : x3;                          \
      a0[2] = lo ? x0 : c2;  a0[3] = lo ? x1 : c3;                          \
      a1[0] = lo ? c4 : x6;  a1[1] = lo ? c5 : x7;                          \
      a1[2] = lo ? x4 : c6;  a1[3] = lo ? x5 : c7;                          \
      pa0 = __builtin_bit_cast(bf16x8, a0);                                 \
      pa1 = __builtin_bit_cast(bf16x8, a1);                                 \
    }                                                                       \
    /* 6. O += P V : 4 d-blocks x 2 k-halves, B = V^T rows from LDS */      \
    __builtin_amdgcn_s_setprio(1);                                          \
    _Pragma("unroll")                                                       \
    for (int nb = 0; nb < 4; ++nb) {                                        \
      const int vrw0 = nb * 32 + l31;                                       \
      const bf16x8 vf0 = *(const bf16x8*)&Vt[vrw0 * VT_STRIDE + swz(vrw0, hi8)]; \
      acc[nb] = __builtin_amdgcn_mfma_f32_32x32x16_bf16(pa0, vf0, acc[nb], 0, 0, 0); \
      const bf16x8 vf1 = *(const bf16x8*)&Vt[vrw0 * VT_STRIDE + swz(vrw0, 16 + hi8)]; \
      acc[nb] = __builtin_amdgcn_mfma_f32_32x32x16_bf16(pa1, vf1, acc[nb], 0, 0, 0); \
    }                                                                       \
    __builtin_amdgcn_s_setprio(0);                                          \
    /* 7. protect LDS before next overwrite */                              \
    barrier_lgkm();                                                         \
  }

// launch_bounds(256, 2): ~120 live regs (R8-measured level). DO NOT raise
// waves/EU ((256,4) spilled 2.5 GB, twice) and DO NOT add prefetch regs
// beyond 8 i32x4 masks (spills at ~128 arch-VGPRs: R3, R9).
// Grid 512 = exactly 2 blocks/CU. LDS: Ks 8704 + Vt 10240 = 18944 B.
__global__ __launch_bounds__(256, 2) void attn_fwd(
    const float* __restrict__ Q, const float* __restrict__ K,
    const float* __restrict__ V, const int* __restrict__ Mask,
    float* __restrict__ Out) {
  // XCD-aware bijective decode: xcd = id%8 (HW round-robin). Each XCD gets
  // bh in [4*xcd, 4*xcd+4), qblk sequential -> K/V (2MB/bh) L2-resident,
  // mask stream order de-thrashes L3 across dispatches (R9: FETCH 651->391).
  const int id   = blockIdx.x;
  const int xcd  = id & 7;
  const int sub  = id >> 3;          // 0..63
  const int bh   = xcd * 4 + (sub >> 4);
  const int qblk = sub & 15;

  const int tid  = threadIdx.x;
  const int w    = tid >> 6;
  const int lane = tid & 63;
  const int l31  = lane & 31;
  const int hi   = lane >> 5;
  const int hi8  = hi * 8;
  const bool lo  = (hi == 0);

  const float* Qg = Q + (size_t)bh * Lc_ * Dc_;
  const float* Kg = K + (size_t)bh * Lc_ * Dc_;
  const float* Vg = V + (size_t)bh * Lc_ * Dc_;
  const int*   Mg = Mask + (size_t)bh * Lc_ * Lc_;
  float*       Og = Out + (size_t)bh * Lc_ * Dc_;

  const int qr0 = qblk * BR + w * 32;

  __shared__ alignas(16) unsigned short Ks[BC * KS_STRIDE];
  __shared__ alignas(16) unsigned short Vt[Dc_ * VT_STRIDE];

  // ---- Q fragments (B-operand of 32x32x16), loaded once, pre-scaled ----
  bf16x8 qf[8];
  {
    const float* qrow = Qg + (size_t)(qr0 + l31) * Dc_ + hi8;
#pragma unroll
    for (int st = 0; st < 8; ++st) {
      const f32x4 a = *(const f32x4*)(qrow + st * 16);
      const f32x4 b = *(const f32x4*)(qrow + st * 16 + 4);
      bf16x8 f;
      f[0] = (short)f2bf(a[0] * SCALE_LOG2E); f[1] = (short)f2bf(a[1] * SCALE_LOG2E);
      f[2] = (short)f2bf(a[2] * SCALE_LOG2E); f[3] = (short)f2bf(a[3] * SCALE_LOG2E);
      f[4] = (short)f2bf(b[0] * SCALE_LOG2E); f[5] = (short)f2bf(b[1] * SCALE_LOG2E);
      f[6] = (short)f2bf(b[2] * SCALE_LOG2E); f[7] = (short)f2bf(b[3] * SCALE_LOG2E);
      qf[st] = f;
    }
  }

  f32x16 acc[4];
#pragma unroll
  for (int i = 0; i < 4; ++i) acc[i] = (f32x16)0.0f;
  float lsum = 0.0f;

  const int krow = tid >> 3;   // 0..31, 8 threads/row (coalesced 64B)
  const int kcg  = tid & 7;
  const int vrow = tid & 31;
  const int vcg  = tid >> 5;

  const float* kbase_g = Kg + (size_t)krow * Dc_ + kcg * 16;
  const float* vbase_g = Vg + (size_t)vrow * Dc_ + vcg * 16;
  const int*   mbase_g = Mg + (size_t)(qr0 + l31) * Lc_ + hi * 4;

  f32x4 kr[4], vr[4];
  i32x4 mA0, mA1, mA2, mA3, mB0, mB1, mB2, mB3;

  kr[0] = *(const f32x4*)(kbase_g + 0);  kr[1] = *(const f32x4*)(kbase_g + 4);
  kr[2] = *(const f32x4*)(kbase_g + 8);  kr[3] = *(const f32x4*)(kbase_g + 12);
  vr[0] = *(const f32x4*)(vbase_g + 0);  vr[1] = *(const f32x4*)(vbase_g + 4);
  vr[2] = *(const f32x4*)(vbase_g + 8);  vr[3] = *(const f32x4*)(vbase_g + 12);
  mA0 = __builtin_nontemporal_load((const i32x4*)(mbase_g));
  mA1 = __builtin_nontemporal_load((const i32x4*)(mbase_g + 8));
  mA2 = __builtin_nontemporal_load((const i32x4*)(mbase_g + 16));
  mA3 = __builtin_nontemporal_load((const i32x4*)(mbase_g + 24));

#pragma unroll 1
  for (int kb = 0; kb < Lc_; kb += 2 * BC) {
    TILE_BODY(kb,      mA, mB)
    TILE_BODY(kb + BC, mB, mA)
  }

  // ---- epilogue: combine k-halves' sums, normalize, store ----
  lsum += __shfl_xor(lsum, 32);
  const float inv = 1.0f / lsum;
#pragma unroll
  for (int r = 0; r < 16; ++r) {
    const int qrow_r = (r & 3) + 8 * (r >> 2) + 4 * hi;
    const float rinv = __shfl(inv, qrow_r);
    float* orow = Og + (size_t)(qr0 + qrow_r) * Dc_ + l31;
#pragma unroll
    for (int nb = 0; nb < 4; ++nb)
      __builtin_nontemporal_store(acc[nb][r] * rinv, orow + nb * 32);
  }
}

extern "C" void kernel_launch(void* const* d_in, const int* in_sizes, int n_in,
                              void* d_out, int out_size, void* d_ws, size_t ws_size,
                              hipStream_t stream) {
  const float* Q    = (const float*)d_in[0];
  const float* K    = (const float*)d_in[1];
  const float* V    = (const float*)d_in[2];
  const int*   Mask = (const int*)d_in[3];
  float*       Out  = (float*)d_out;
  (void)d_ws; (void)ws_size;
  attn_fwd<<<dim3(512), dim3(256), 0, stream>>>(Q, K, V, Mask, Out);
}

// Round 11
// 812.264 us; speedup vs baseline: 1.1401x; 1.0391x over previous
//
#include <hip/hip_runtime.h>
#include <math.h>

// Problem constants (B=2, H=16, L=2048, D=128, fp32 in/out, int32 mask)
constexpr int Bc_ = 2;
constexpr int Hc_ = 16;
constexpr int Lc_ = 2048;
constexpr int Dc_ = 128;
constexpr int BR  = 128;  // Q rows per block (4 waves x 32 rows, 32x32 MFMA)
constexpr int BC  = 32;   // K rows per tile
// 1/sqrt(128) * log2(e): exp(x) == exp2(x*log2e); fold log2e into Q pre-scale.
constexpr float SCALE_LOG2E = 0.08838834764831845f * 1.4426950408889634f;

typedef __attribute__((ext_vector_type(8)))  short        bf16x8;
typedef __attribute__((ext_vector_type(4)))  float        f32x4;
typedef __attribute__((ext_vector_type(16))) float        f32x16;
typedef __attribute__((ext_vector_type(4)))  int          i32x4;
typedef __attribute__((ext_vector_type(4)))  unsigned int u32x4;

// fp32 -> bf16 RNE (scalar; only for the one-time Q fragment build)
__device__ __forceinline__ unsigned short f2bf(float f) {
  unsigned u = __builtin_bit_cast(unsigned, f);
  return (unsigned short)((u + 0x7fffu + ((u >> 16) & 1u)) >> 16);
}

// packed fp32x2 -> bf16x2 in ONE VALU op
__device__ __forceinline__ unsigned cvt_pk_bf16(float lo, float hi) {
  unsigned r;
  asm("v_cvt_pk_bf16_f32 %0, %1, %2" : "=v"(r) : "v"(lo), "v"(hi));
  return r;
}

// Workgroup barrier that does NOT drain vmcnt (unlike __syncthreads).
// LDS visibility needs lgkmcnt(0) only; register-prefetch global loads
// stay in flight across the barrier.
__device__ __forceinline__ void barrier_lgkm() {
  asm volatile("s_waitcnt lgkmcnt(0)\n\ts_barrier" ::: "memory");
}

constexpr int KS_STRIDE = 136;  // K tile rows (shorts)
constexpr int VT_STRIDE = 40;   // V^T rows (shorts, 32 k-cols + 8 pad)

// XOR swizzle (shorts): rows r, r+8, r+16, r+24 (same base bank-phase) get
// 4 distinct 16B slots. Applied identically on write and read (bijective,
// preserves 16B alignment). R7-verified; conflicts 2.4e7 -> 1.47e7.
__device__ __forceinline__ int swz(int row, int colShorts) {
  return colShorts ^ (((row >> 3) & 3) << 3);
}

// ===========================================================================
// R11 = R10 (best: 844 total, attn ~279us) + two changes:
//  (a) mask loads CACHEABLE (drop nontemporal): R9 proved cross-iteration L3
//      retention of the 537MB mask stream is the active margin (FETCH
//      651->391 from swizzle alone, with nt ON). nt = evict-first hint ->
//      plausibly suppressing further retention. Measur able via FETCH_SIZE.
//  (b) dual-accumulator QK^T: 8 serially-dependent MFMAs -> two independent
//      4-chains (s0 even d-steps, s1 odd), s = s0+s1 (exact fp32 reassoc of
//      the same partials). Halves the per-tile MFMA critical path. +16 VGPR
//      (~136): safe at (256,2) cap 256; occupancy is grid-limited at 2
//      blocks/CU so no cliff (the 128-VGPR danger is only at 4 waves/EU).
// Everything else identical to R10 (verified).
// ===========================================================================
#define TILE_BODY(KB, MC, MN)                                               \
  {                                                                         \
    /* 1. stage current K regs -> LDS (bf16, swizzled row-major) */         \
    {                                                                       \
      u32x4 a, b;                                                           \
      a[0] = cvt_pk_bf16(kr[0][0], kr[0][1]);                               \
      a[1] = cvt_pk_bf16(kr[0][2], kr[0][3]);                               \
      a[2] = cvt_pk_bf16(kr[1][0], kr[1][1]);                               \
      a[3] = cvt_pk_bf16(kr[1][2], kr[1][3]);                               \
      b[0] = cvt_pk_bf16(kr[2][0], kr[2][1]);                               \
      b[1] = cvt_pk_bf16(kr[2][2], kr[2][3]);                               \
      b[2] = cvt_pk_bf16(kr[3][0], kr[3][1]);                               \
      b[3] = cvt_pk_bf16(kr[3][2], kr[3][3]);                               \
      *(u32x4*)&Ks[krow * KS_STRIDE + swz(krow, kcg * 16)]     = a;         \
      *(u32x4*)&Ks[krow * KS_STRIDE + swz(krow, kcg * 16 + 8)] = b;         \
    }                                                                       \
    /* stage current V regs -> LDS transposed (scatter, swizzled) */        \
    _Pragma("unroll")                                                       \
    for (int c4 = 0; c4 < 4; ++c4) {                                        \
      const unsigned lov = cvt_pk_bf16(vr[c4][0], vr[c4][1]);               \
      const unsigned hiv = cvt_pk_bf16(vr[c4][2], vr[c4][3]);               \
      const int r0 = vcg * 16 + c4 * 4;                                     \
      Vt[(r0 + 0) * VT_STRIDE + swz(r0 + 0, vrow)] = (unsigned short)lov;   \
      Vt[(r0 + 1) * VT_STRIDE + swz(r0 + 1, vrow)] = (unsigned short)(lov >> 16); \
      Vt[(r0 + 2) * VT_STRIDE + swz(r0 + 2, vrow)] = (unsigned short)hiv;   \
      Vt[(r0 + 3) * VT_STRIDE + swz(r0 + 3, vrow)] = (unsigned short)(hiv >> 16); \
    }                                                                       \
    /* 2. issue next-tile K/V + mask loads (1-deep). All stay in flight     \
          across the lgkm-only barrier; tile body (~5k cyc) covers latency. */ \
    {                                                                       \
      const int kbn = ((KB) + BC) & (Lc_ - 1);                              \
      const float* kp = kbase_g + (size_t)kbn * Dc_;                        \
      const float* vp = vbase_g + (size_t)kbn * Dc_;                        \
      kr[0] = *(const f32x4*)(kp + 0);  kr[1] = *(const f32x4*)(kp + 4);    \
      kr[2] = *(const f32x4*)(kp + 8);  kr[3] = *(const f32x4*)(kp + 12);   \
      vr[0] = *(const f32x4*)(vp + 0);  vr[1] = *(const f32x4*)(vp + 4);    \
      vr[2] = *(const f32x4*)(vp + 8);  vr[3] = *(const f32x4*)(vp + 12);   \
      MN##0 = *(const i32x4*)(mbase_g + kbn);                               \
      MN##1 = *(const i32x4*)(mbase_g + kbn + 8);                           \
      MN##2 = *(const i32x4*)(mbase_g + kbn + 16);                          \
      MN##3 = *(const i32x4*)(mbase_g + kbn + 24);                          \
    }                                                                       \
    /* 3. barrier (lgkm only) — publishes Ks/Vt */                          \
    barrier_lgkm();                                                         \
    /* 4. S^T = K (Q*scale)^T : 8 MFMAs as TWO independent 4-chains */      \
    f32x16 s0 = (f32x16)0.0f, s1 = (f32x16)0.0f;                            \
    __builtin_amdgcn_s_setprio(1);                                          \
    _Pragma("unroll")                                                       \
    for (int st = 0; st < 8; st += 2) {                                     \
      const bf16x8 kf0 = *(const bf16x8*)&Ks[l31 * KS_STRIDE + swz(l31, st * 16 + hi8)]; \
      s0 = __builtin_amdgcn_mfma_f32_32x32x16_bf16(kf0, qf[st], s0, 0, 0, 0); \
      const bf16x8 kf1 = *(const bf16x8*)&Ks[l31 * KS_STRIDE + swz(l31, (st + 1) * 16 + hi8)]; \
      s1 = __builtin_amdgcn_mfma_f32_32x32x16_bf16(kf1, qf[st + 1], s1, 0, 0, 0); \
    }                                                                       \
    __builtin_amdgcn_s_setprio(0);                                          \
    const f32x16 s = s0 + s1;                                               \
    /* 5. p = mask ? exp2(s) : 0 ; per-lane scalar row-sum; PV A-frags in   \
          register via cvt_pk + cross-half exchange (no LDS). */            \
    bf16x8 pa0, pa1;                                                        \
    {                                                                       \
      const float p0  = ((MC##0)[0] != 0) ? exp2f(s[0])  : 0.0f;            \
      const float p1  = ((MC##0)[1] != 0) ? exp2f(s[1])  : 0.0f;            \
      const float p2  = ((MC##0)[2] != 0) ? exp2f(s[2])  : 0.0f;            \
      const float p3  = ((MC##0)[3] != 0) ? exp2f(s[3])  : 0.0f;            \
      const float p4  = ((MC##1)[0] != 0) ? exp2f(s[4])  : 0.0f;            \
      const float p5  = ((MC##1)[1] != 0) ? exp2f(s[5])  : 0.0f;            \
      const float p6  = ((MC##1)[2] != 0) ? exp2f(s[6])  : 0.0f;            \
      const float p7  = ((MC##1)[3] != 0) ? exp2f(s[7])  : 0.0f;            \
      const float p8  = ((MC##2)[0] != 0) ? exp2f(s[8])  : 0.0f;            \
      const float p9  = ((MC##2)[1] != 0) ? exp2f(s[9])  : 0.0f;            \
      const float p10 = ((MC##2)[2] != 0) ? exp2f(s[10]) : 0.0f;            \
      const float p11 = ((MC##2)[3] != 0) ? exp2f(s[11]) : 0.0f;            \
      const float p12 = ((MC##3)[0] != 0) ? exp2f(s[12]) : 0.0f;            \
      const float p13 = ((MC##3)[1] != 0) ? exp2f(s[13]) : 0.0f;            \
      const float p14 = ((MC##3)[2] != 0) ? exp2f(s[14]) : 0.0f;            \
      const float p15 = ((MC##3)[3] != 0) ? exp2f(s[15]) : 0.0f;            \
      lsum += (((p0 + p1) + (p2 + p3)) + ((p4 + p5) + (p6 + p7)))           \
            + (((p8 + p9) + (p10 + p11)) + ((p12 + p13) + (p14 + p15)));    \
      const unsigned c0 = cvt_pk_bf16(p0,  p1),  c1 = cvt_pk_bf16(p2,  p3); \
      const unsigned c2 = cvt_pk_bf16(p4,  p5),  c3 = cvt_pk_bf16(p6,  p7); \
      const unsigned c4 = cvt_pk_bf16(p8,  p9),  c5 = cvt_pk_bf16(p10, p11);\
      const unsigned c6 = cvt_pk_bf16(p12, p13), c7 = cvt_pk_bf16(p14, p15);\
      const unsigned x0 = (unsigned)__shfl_xor((int)c0, 32);                \
      const unsigned x1 = (unsigned)__shfl_xor((int)c1, 32);                \
      const unsigned x2 = (unsigned)__shfl_xor((int)c2, 32);                \
      const unsigned x3 = (unsigned)__shfl_xor((int)c3, 32);                \
      const unsigned x4 = (unsigned)__shfl_xor((int)c4, 32);                \
      const unsigned x5 = (unsigned)__shfl_xor((int)c5, 32);                \
      const unsigned x6 = (unsigned)__shfl_xor((int)c6, 32);                \
      const unsigned x7 = (unsigned)__shfl_xor((int)c7, 32);                \
      u32x4 a0, a1;                                                         \
      a0[0] = lo ? c0 : x2;  a0[1] = lo ? c1 : x3;                          \
      a0[2] = lo ? x0 : c2;  a0[3] = lo ? x1 : c3;                          \
      a1[0] = lo ? c4 : x6;  a1[1] = lo ? c5 : x7;                          \
      a1[2] = lo ? x4 : c6;  a1[3] = lo ? x5 : c7;                          \
      pa0 = __builtin_bit_cast(bf16x8, a0);                                 \
      pa1 = __builtin_bit_cast(bf16x8, a1);                                 \
    }                                                                       \
    /* 6. O += P V : 4 d-blocks x 2 k-halves, B = V^T rows from LDS */      \
    __builtin_amdgcn_s_setprio(1);                                          \
    _Pragma("unroll")                                                       \
    for (int nb = 0; nb < 4; ++nb) {                                        \
      const int vrw0 = nb * 32 + l31;                                       \
      const bf16x8 vf0 = *(const bf16x8*)&Vt[vrw0 * VT_STRIDE + swz(vrw0, hi8)]; \
      acc[nb] = __builtin_amdgcn_mfma_f32_32x32x16_bf16(pa0, vf0, acc[nb], 0, 0, 0); \
      const bf16x8 vf1 = *(const bf16x8*)&Vt[vrw0 * VT_STRIDE + swz(vrw0, 16 + hi8)]; \
      acc[nb] = __builtin_amdgcn_mfma_f32_32x32x16_bf16(pa1, vf1, acc[nb], 0, 0, 0); \
    }                                                                       \
    __builtin_amdgcn_s_setprio(0);                                          \
    /* 7. protect LDS before next overwrite */                              \
    barrier_lgkm();                                                         \
  }

// launch_bounds(256, 2): ~136 est. live regs (R10's 120 + 16 dual-acc).
// Safe: cap 256 at 2 waves/EU, and occupancy is grid-limited (512 blocks =
// 2/CU) so extra regs cost nothing. DO NOT go to 4 waves/EU ((256,4)
// spilled 2.5 GB, twice) or add prefetch regs (spills at ~128+: R3, R9).
// Grid 512 = exactly 2 blocks/CU. LDS: Ks 8704 + Vt 10240 = 18944 B.
__global__ __launch_bounds__(256, 2) void attn_fwd(
    const float* __restrict__ Q, const float* __restrict__ K,
    const float* __restrict__ V, const int* __restrict__ Mask,
    float* __restrict__ Out) {
  // XCD-aware bijective decode: xcd = id%8 (HW round-robin). Each XCD gets
  // bh in [4*xcd, 4*xcd+4), qblk sequential -> K/V (2MB/bh) L2-resident,
  // mask stream order de-thrashes L3 across dispatches (R9: FETCH 651->391).
  const int id   = blockIdx.x;
  const int xcd  = id & 7;
  const int sub  = id >> 3;          // 0..63
  const int bh   = xcd * 4 + (sub >> 4);
  const int qblk = sub & 15;

  const int tid  = threadIdx.x;
  const int w    = tid >> 6;
  const int lane = tid & 63;
  const int l31  = lane & 31;
  const int hi   = lane >> 5;
  const int hi8  = hi * 8;
  const bool lo  = (hi == 0);

  const float* Qg = Q + (size_t)bh * Lc_ * Dc_;
  const float* Kg = K + (size_t)bh * Lc_ * Dc_;
  const float* Vg = V + (size_t)bh * Lc_ * Dc_;
  const int*   Mg = Mask + (size_t)bh * Lc_ * Lc_;
  float*       Og = Out + (size_t)bh * Lc_ * Dc_;

  const int qr0 = qblk * BR + w * 32;

  __shared__ alignas(16) unsigned short Ks[BC * KS_STRIDE];
  __shared__ alignas(16) unsigned short Vt[Dc_ * VT_STRIDE];

  // ---- Q fragments (B-operand of 32x32x16), loaded once, pre-scaled ----
  bf16x8 qf[8];
  {
    const float* qrow = Qg + (size_t)(qr0 + l31) * Dc_ + hi8;
#pragma unroll
    for (int st = 0; st < 8; ++st) {
      const f32x4 a = *(const f32x4*)(qrow + st * 16);
      const f32x4 b = *(const f32x4*)(qrow + st * 16 + 4);
      bf16x8 f;
      f[0] = (short)f2bf(a[0] * SCALE_LOG2E); f[1] = (short)f2bf(a[1] * SCALE_LOG2E);
      f[2] = (short)f2bf(a[2] * SCALE_LOG2E); f[3] = (short)f2bf(a[3] * SCALE_LOG2E);
      f[4] = (short)f2bf(b[0] * SCALE_LOG2E); f[5] = (short)f2bf(b[1] * SCALE_LOG2E);
      f[6] = (short)f2bf(b[2] * SCALE_LOG2E); f[7] = (short)f2bf(b[3] * SCALE_LOG2E);
      qf[st] = f;
    }
  }

  f32x16 acc[4];
#pragma unroll
  for (int i = 0; i < 4; ++i) acc[i] = (f32x16)0.0f;
  float lsum = 0.0f;

  const int krow = tid >> 3;   // 0..31, 8 threads/row (coalesced 64B)
  const int kcg  = tid & 7;
  const int vrow = tid & 31;
  const int vcg  = tid >> 5;

  const float* kbase_g = Kg + (size_t)krow * Dc_ + kcg * 16;
  const float* vbase_g = Vg + (size_t)vrow * Dc_ + vcg * 16;
  const int*   mbase_g = Mg + (size_t)(qr0 + l31) * Lc_ + hi * 4;

  f32x4 kr[4], vr[4];
  i32x4 mA0, mA1, mA2, mA3, mB0, mB1, mB2, mB3;

  kr[0] = *(const f32x4*)(kbase_g + 0);  kr[1] = *(const f32x4*)(kbase_g + 4);
  kr[2] = *(const f32x4*)(kbase_g + 8);  kr[3] = *(const f32x4*)(kbase_g + 12);
  vr[0] = *(const f32x4*)(vbase_g + 0);  vr[1] = *(const f32x4*)(vbase_g + 4);
  vr[2] = *(const f32x4*)(vbase_g + 8);  vr[3] = *(const f32x4*)(vbase_g + 12);
  mA0 = *(const i32x4*)(mbase_g);
  mA1 = *(const i32x4*)(mbase_g + 8);
  mA2 = *(const i32x4*)(mbase_g + 16);
  mA3 = *(const i32x4*)(mbase_g + 24);

#pragma unroll 1
  for (int kb = 0; kb < Lc_; kb += 2 * BC) {
    TILE_BODY(kb,      mA, mB)
    TILE_BODY(kb + BC, mB, mA)
  }

  // ---- epilogue: combine k-halves' sums, normalize, store ----
  lsum += __shfl_xor(lsum, 32);
  const float inv = 1.0f / lsum;
#pragma unroll
  for (int r = 0; r < 16; ++r) {
    const int qrow_r = (r & 3) + 8 * (r >> 2) + 4 * hi;
    const float rinv = __shfl(inv, qrow_r);
    float* orow = Og + (size_t)(qr0 + qrow_r) * Dc_ + l31;
#pragma unroll
    for (int nb = 0; nb < 4; ++nb)
      __builtin_nontemporal_store(acc[nb][r] * rinv, orow + nb * 32);
  }
}

extern "C" void kernel_launch(void* const* d_in, const int* in_sizes, int n_in,
                              void* d_out, int out_size, void* d_ws, size_t ws_size,
                              hipStream_t stream) {
  const float* Q    = (const float*)d_in[0];
  const float* K    = (const float*)d_in[1];
  const float* V    = (const float*)d_in[2];
  const int*   Mask = (const int*)d_in[3];
  float*       Out  = (float*)d_out;
  (void)d_ws; (void)ws_size;
  attn_fwd<<<dim3(512), dim3(256), 0, stream>>>(Q, K, V, Mask, Out);
}